// Round 10
// baseline (441.941 us; speedup 1.0000x reference)
//
#include <hip/hip_runtime.h>
#include <stdint.h>

#define B_ 1024
#define D_ 784
#define H_ 1024
#define BH_ (B_ * H_)
#define LOG2E 1.4426950408889634f

// Segments: {0,132,264,396,528,656,784}; G ranges: first 5 spans.
// ws: VW [788][4][512] interleaved (V|W*log2e) 6.45 MB | G [5][B][H] 21 MB | part [4][B][D] 12.8 MB

typedef float v2f __attribute__((ext_vector_type(2)));

__device__ __forceinline__ v2f pk_fma(v2f a, v2f b, v2f c) {
    v2f d; asm("v_pk_fma_f32 %0, %1, %2, %3" : "=v"(d) : "v"(a), "v"(b), "v"(c)); return d;
}
__device__ __forceinline__ v2f pk_add(v2f a, v2f b) {
    v2f d; asm("v_pk_add_f32 %0, %1, %2" : "=v"(d) : "v"(a), "v"(b)); return d;
}
__device__ __forceinline__ v2f pk_sub(v2f a, v2f b) {
    v2f d; asm("v_pk_add_f32 %0, %1, %2 neg_lo:[0,1] neg_hi:[0,1]" : "=v"(d) : "v"(a), "v"(b)); return d;
}
__device__ __forceinline__ v2f pk_mul(v2f a, v2f b) {
    v2f d; asm("v_pk_mul_f32 %0, %1, %2" : "=v"(d) : "v"(a), "v"(b)); return d;
}

__device__ __forceinline__ int seg_bound(int s) {
    const int b[7] = {0, 132, 264, 396, 528, 656, 784};
    return b[s];
}

// ---------- fat prep (identical to R7) ----------
__global__ __launch_bounds__(256) void prep(const float* __restrict__ V,
                                            const float* __restrict__ W,
                                            const float* __restrict__ px,
                                            float* __restrict__ VW,
                                            float* __restrict__ G) {
    __shared__ float smem[32 * 33];
    const int t = threadIdx.x;

    if (blockIdx.x < 800) {
        int i0 = (blockIdx.x % 25) * 32;
        int h0 = (blockIdx.x / 25) * 32;
        int tx = t & 31, ty = t >> 5;   // 32 x 8
        int hb = h0 >> 8, hl = h0 & 255;
#pragma unroll
        for (int j = 0; j < 4; ++j) {
            int i = i0 + ty + j * 8;
            if (i < D_)
                VW[((size_t)i * 4 + hb) * 512 + hl + tx] = V[(size_t)i * H_ + h0 + tx];
        }
#pragma unroll
        for (int j = 0; j < 4; ++j) {
            int h = h0 + ty + j * 8;
            int i = i0 + tx;
            float v = 0.f;
            if (i < D_) v = W[(size_t)h * D_ + i] * LOG2E;
            smem[(ty + j * 8) * 33 + tx] = v;
        }
        __syncthreads();
#pragma unroll
        for (int j = 0; j < 4; ++j) {
            int i = i0 + ty + j * 8;
            if (i < D_)
                VW[((size_t)i * 4 + hb) * 512 + 256 + hl + tx] = smem[tx * 33 + ty + j * 8];
        }
    } else {
        float* xs = smem;          // [4][64]
        float* ws = smem + 256;    // [4][64]
        int idx = blockIdx.x - 800;
        int r   = idx >> 8;                       // 0..4
        int b0  = (idx & 15) * 64;
        int h0  = ((idx >> 4) & 15) * 64;
        int j0s = seg_bound(r), j1s = seg_bound(r + 1);

        const int tb = t >> 4, th = t & 15;       // 16x16, each 4b x 4h
        float acc[4][4];
#pragma unroll
        for (int bi = 0; bi < 4; ++bi)
#pragma unroll
            for (int hh = 0; hh < 4; ++hh) acc[bi][hh] = 0.f;

        for (int j0 = j0s; j0 < j1s; j0 += 4) {
            float xv = px[(size_t)(b0 + (t >> 2)) * D_ + j0 + (t & 3)];
            float4 wv = make_float4(0, 0, 0, 0);
            if (t < 64) wv = *(const float4*)(W + (size_t)(h0 + t) * D_ + j0);
            __syncthreads();
            xs[(t & 3) * 64 + (t >> 2)] = xv;
            if (t < 64) {
                ws[0 * 64 + t] = wv.x * LOG2E;
                ws[1 * 64 + t] = wv.y * LOG2E;
                ws[2 * 64 + t] = wv.z * LOG2E;
                ws[3 * 64 + t] = wv.w * LOG2E;
            }
            __syncthreads();
#pragma unroll
            for (int jj = 0; jj < 4; ++jj) {
                float4 xb = *(float4*)&xs[jj * 64 + tb * 4];
                float4 wb = *(float4*)&ws[jj * 64 + th * 4];
                float xa[4] = {xb.x, xb.y, xb.z, xb.w};
                float wa[4] = {wb.x, wb.y, wb.z, wb.w};
#pragma unroll
                for (int bi = 0; bi < 4; ++bi)
#pragma unroll
                    for (int hh = 0; hh < 4; ++hh)
                        acc[bi][hh] = fmaf(xa[bi], wa[hh], acc[bi][hh]);
            }
        }
        float* dst = G + (size_t)r * BH_;
#pragma unroll
        for (int bi = 0; bi < 4; ++bi) {
            float4 o = make_float4(acc[bi][0], acc[bi][1], acc[bi][2], acc[bi][3]);
            *(float4*)(dst + (size_t)(b0 + tb * 4 + bi) * H_ + h0 + th * 4) = o;
        }
    }
}

// ---------- DPP reduce: both 32-lane halves simultaneously ----------
template <int CTRL>
__device__ __forceinline__ float dpp_add(float p) {
    int s = __builtin_amdgcn_update_dpp(0, __float_as_int(p), CTRL, 0xf, 0xf, true);
    return p + __int_as_float(s);
}
__device__ __forceinline__ float reduce_halves(float p) {
    p = dpp_add<0x111>(p);
    p = dpp_add<0x112>(p);
    p = dpp_add<0x114>(p);
    p = dpp_add<0x118>(p);
    p = dpp_add<0x142>(p);   // lane31 = sum(0..31), lane63 = sum(32..63)
    return p;
}

// ---------- main scan: R7 geometry + packed software exp2 ----------
__global__ __launch_bounds__(256, 6) void nade_main(
    const float* __restrict__ px,   // [B, D]
    const float* __restrict__ c,    // [H]
    const float* __restrict__ VW,   // [788][4][512] interleaved
    const float* __restrict__ G,    // [5][B][H] (log2 domain)
    float* __restrict__ part)       // [4][B][D]
{
    const int lane = threadIdx.x & 63;
    const int wid  = threadIdx.x >> 6;
    const int gw   = blockIdx.x * 4 + wid;   // 0..12287
    const int s    = gw % 6;
    const int r4   = gw / 6;                 // 0..2047
    const int hb   = r4 & 3;
    const int rp   = r4 >> 2;                // 0..511
    const int half = lane >> 5;
    const int row  = rp * 2 + half;
    const int hl   = lane & 31;
    const int h0   = hb * 256 + hl * 8;

    const int i0s = seg_bound(s), i1s = seg_bound(s + 1);

    // A (log2 domain) = c*log2e + sum_{r<s} G_r, held as v2f pairs
    v2f A01, A23, A45, A67;
    {
        float4 c0 = *(const float4*)(c + h0);
        float4 c1 = *(const float4*)(c + h0 + 4);
        A01 = (v2f){c0.x * LOG2E, c0.y * LOG2E};
        A23 = (v2f){c0.z * LOG2E, c0.w * LOG2E};
        A45 = (v2f){c1.x * LOG2E, c1.y * LOG2E};
        A67 = (v2f){c1.z * LOG2E, c1.w * LOG2E};
        for (int r = 0; r < s; ++r) {
            const float* gp = G + (size_t)r * BH_ + (size_t)row * H_ + h0;
            float4 g0 = *(const float4*)(gp);
            float4 g1 = *(const float4*)(gp + 4);
            A01 = pk_add(A01, (v2f){g0.x, g0.y});
            A23 = pk_add(A23, (v2f){g0.z, g0.w});
            A45 = pk_add(A45, (v2f){g1.x, g1.y});
            A67 = pk_add(A67, (v2f){g1.z, g1.w});
        }
    }

    const float* xp = px + (size_t)row * D_;
    float*       pp = part + ((size_t)hb * B_ + row) * D_;
    const float* vw = VW + ((size_t)i0s * 4 + hb) * 512 + hl * 8;

    // hoisted packed constants
    const v2f MG  = {12582912.f, 12582912.f};          // 1.5 * 2^23
    const v2f C4  = {0.0096181291f, 0.0096181291f};
    const v2f C3  = {0.0555041087f, 0.0555041087f};
    const v2f C2  = {0.2402265070f, 0.2402265070f};
    const v2f C1  = {0.6931471806f, 0.6931471806f};
    const v2f ONE = {1.f, 1.f};

    // q = 1 + 2^t for a pair, t = clamp(-A, -126, 15) via scalar med3 (neg is free src-mod)
    auto q_pair = [&](v2f A) -> v2f {
        v2f t;
        t.x = __builtin_amdgcn_fmed3f(-A.x, -126.f, 15.f);
        t.y = __builtin_amdgcn_fmed3f(-A.y, -126.f, 15.f);
        v2f m = pk_add(t, MG);
        v2f f = pk_sub(t, pk_sub(m, MG));
        v2f p = pk_fma(C4, f, C3);
        p = pk_fma(p, f, C2);
        p = pk_fma(p, f, C1);
        p = pk_mul(p, f);                       // p = 2^f - 1 (deg-4)
        v2f sc;
        sc.x = __uint_as_float((__float_as_uint(m.x) << 23) + 0x3F800000u);
        sc.y = __uint_as_float((__float_as_uint(m.y) << 23) + 0x3F800000u);
        v2f e = pk_fma(sc, p, sc);              // 2^t = sc * (1 + p)
        return pk_add(e, ONE);                  // q = 1 + 2^t
    };

    // one step (8 h): pk soft-exp2, one hw rcp per 8
    auto step8 = [&](const float4& v0f, const float4& v1f,
                     const float4& w0f, const float4& w1f, float xi) -> float {
        v2f q0 = q_pair(A01);
        v2f q1 = q_pair(A23);
        v2f q2 = q_pair(A45);
        v2f q3 = q_pair(A67);
        v2f xx = {xi, xi};
        A01 = pk_fma((v2f){w0f.x, w0f.y}, xx, A01);
        A23 = pk_fma((v2f){w0f.z, w0f.w}, xx, A23);
        A45 = pk_fma((v2f){w1f.x, w1f.y}, xx, A45);
        A67 = pk_fma((v2f){w1f.z, w1f.w}, xx, A67);
        float a01 = fmaf(v0f.x, q0.y, v0f.y * q0.x);
        float a23 = fmaf(v0f.z, q1.y, v0f.w * q1.x);
        float a45 = fmaf(v1f.x, q2.y, v1f.y * q2.x);
        float a67 = fmaf(v1f.z, q3.y, v1f.w * q3.x);
        float q01 = q0.x * q0.y, q23 = q1.x * q1.y;
        float q45 = q2.x * q2.y, q67 = q3.x * q3.y;
        float n0123 = fmaf(a01, q23, a23 * q01);
        float n4567 = fmaf(a45, q67, a67 * q45);
        float q0123 = q01 * q23, q4567 = q45 * q67;
        float r = __builtin_amdgcn_rcpf(q0123 * q4567);
        float n = fmaf(n0123, q4567, n4567 * q0123);
        return n * r;
    };

    // preload current quad + first x group
    float4 v0 = *(const float4*)(vw + 0),   v1 = *(const float4*)(vw + 4);
    float4 w0 = *(const float4*)(vw + 256), w1 = *(const float4*)(vw + 260);
    vw += 2048;
    float4 xq = *(const float4*)(xp + i0s);

    for (int ib = i0s; ib < i1s; ib += 4) {     // all segment lengths %4 == 0
        int xb = (ib + 4 < i1s) ? (ib + 4) : i0s;
        float4 xq_n = *(const float4*)(xp + xb);
        float xa[4] = {xq.x, xq.y, xq.z, xq.w};
        float pr[4];
#pragma unroll
        for (int j = 0; j < 4; ++j) {
            float4 v0n = *(const float4*)(vw + 0),   v1n = *(const float4*)(vw + 4);
            float4 w0n = *(const float4*)(vw + 256), w1n = *(const float4*)(vw + 260);
            vw += 2048;
            float p = step8(v0, v1, w0, w1, xa[j]);
            pr[j] = reduce_halves(p);
            v0 = v0n; v1 = v1n; w0 = w0n; w1 = w1n;
        }
        if (hl == 31) *(float4*)(pp + ib) = make_float4(pr[0], pr[1], pr[2], pr[3]);
        xq = xq_n;
    }
}

// ---------- epilogue: out[row][i] = bias[i] + sum_hb part[hb][row][i] ----------
__global__ __launch_bounds__(256) void reduce_out(const float* __restrict__ part,
                                                  const float* __restrict__ bias,
                                                  float* __restrict__ out) {
    int t = blockIdx.x * 256 + threadIdx.x;
    if (t >= B_ * (D_ / 4)) return;
    int row = t / (D_ / 4);
    int ic  = (t - row * (D_ / 4)) * 4;
    float4 acc = *(const float4*)(bias + ic);
    const float* p = part + (size_t)row * D_ + ic;
#pragma unroll
    for (int hb = 0; hb < 4; ++hb) {
        float4 v = *(const float4*)(p + (size_t)hb * B_ * D_);
        acc.x += v.x; acc.y += v.y; acc.z += v.z; acc.w += v.w;
    }
    *(float4*)(out + (size_t)row * D_ + ic) = acc;
}

extern "C" void kernel_launch(void* const* d_in, const int* in_sizes, int n_in,
                              void* d_out, int out_size, void* d_ws, size_t ws_size,
                              hipStream_t stream) {
    const float* px   = (const float*)d_in[0];  // [B, D]
    const float* W    = (const float*)d_in[1];  // [H, D]
    const float* c    = (const float*)d_in[2];  // [H]
    const float* V    = (const float*)d_in[3];  // [D, H]
    const float* bias = (const float*)d_in[4];  // [D]
    float* out = (float*)d_out;                 // [B, D]

    float* VW   = (float*)d_ws;                 // 788*2048 floats = 6.45 MB
    float* G    = VW + (size_t)788 * 2048;      // [5][B][H]
    float* part = G + (size_t)5 * BH_;          // [4][B][D]

    prep<<<dim3(2080), 256, 0, stream>>>(V, W, px, VW, G);

    // 3072 blocks x 4 waves = 12288 waves = 2 residency rounds at 6 waves/SIMD
    nade_main<<<dim3(3072), 256, 0, stream>>>(px, c, VW, G, part);

    reduce_out<<<dim3((B_ * (D_ / 4) + 255) / 256), 256, 0, stream>>>(part, bias, out);
}

// Round 11
// 309.951 us; speedup vs baseline: 1.4258x; 1.4258x over previous
//
#include <hip/hip_runtime.h>
#include <stdint.h>

#define B_ 1024
#define D_ 784
#define H_ 1024
#define BH_ (B_ * H_)
#define LOG2E 1.4426950408889634f

// Segments: {0,132,264,396,528,656,784}; G ranges: first 5 spans.
// VWb: per (step i, hb) a 1KB image of 512 ushorts: [0,256) = V bf16, [256,512) = W*log2e bf16.
//      lane reads V as uint4 at ushort offset hl*8, W at 256+hl*8.
// ws: VWb [788][4][512] ushort 3.23 MB | G [5][B][H] fp32 21 MB | part [4][B][D] 12.8 MB

__device__ __forceinline__ unsigned short bf16_rne(float x) {
    unsigned b = __float_as_uint(x);
    return (unsigned short)((b + 0x7FFFu + ((b >> 16) & 1u)) >> 16);
}

__device__ __forceinline__ int seg_bound(int s) {
    const int b[7] = {0, 132, 264, 396, 528, 656, 784};
    return b[s];
}

// ---------- fat prep ----------
// blocks [0,800): build VWb (V + W^T*log2e, both bf16-RNE); blocks [800,2080): G partial GEMMs (fp32)
__global__ __launch_bounds__(256) void prep(const float* __restrict__ V,
                                            const float* __restrict__ W,
                                            const float* __restrict__ px,
                                            unsigned short* __restrict__ VWb,
                                            float* __restrict__ G) {
    __shared__ float smem[32 * 33];
    const int t = threadIdx.x;

    if (blockIdx.x < 800) {
        int i0 = (blockIdx.x % 25) * 32;
        int h0 = (blockIdx.x / 25) * 32;
        int tx = t & 31, ty = t >> 5;   // 32 x 8
        int hb = h0 >> 8, hr = h0 & 255;
        // V -> bf16 image
#pragma unroll
        for (int j = 0; j < 4; ++j) {
            int i = i0 + ty + j * 8;
            if (i < D_)
                VWb[((size_t)i * 4 + hb) * 512 + hr + tx] = bf16_rne(V[(size_t)i * H_ + h0 + tx]);
        }
        // W transpose via LDS, *log2e, -> bf16 image
#pragma unroll
        for (int j = 0; j < 4; ++j) {
            int h = h0 + ty + j * 8;
            int i = i0 + tx;
            float v = 0.f;
            if (i < D_) v = W[(size_t)h * D_ + i] * LOG2E;
            smem[(ty + j * 8) * 33 + tx] = v;
        }
        __syncthreads();
#pragma unroll
        for (int j = 0; j < 4; ++j) {
            int i = i0 + ty + j * 8;
            if (i < D_)
                VWb[((size_t)i * 4 + hb) * 512 + 256 + hr + tx] = bf16_rne(smem[tx * 33 + ty + j * 8]);
        }
    } else {
        float* xs = smem;          // [4][64]
        float* ws = smem + 256;    // [4][64]
        int idx = blockIdx.x - 800;
        int r   = idx >> 8;                       // 0..4
        int b0  = (idx & 15) * 64;
        int h0  = ((idx >> 4) & 15) * 64;
        int j0s = seg_bound(r), j1s = seg_bound(r + 1);

        const int tb = t >> 4, th = t & 15;       // 16x16, each 4b x 4h
        float acc[4][4];
#pragma unroll
        for (int bi = 0; bi < 4; ++bi)
#pragma unroll
            for (int hh = 0; hh < 4; ++hh) acc[bi][hh] = 0.f;

        for (int j0 = j0s; j0 < j1s; j0 += 4) {
            float xv = px[(size_t)(b0 + (t >> 2)) * D_ + j0 + (t & 3)];
            float4 wv = make_float4(0, 0, 0, 0);
            if (t < 64) wv = *(const float4*)(W + (size_t)(h0 + t) * D_ + j0);
            __syncthreads();
            xs[(t & 3) * 64 + (t >> 2)] = xv;
            if (t < 64) {
                ws[0 * 64 + t] = wv.x * LOG2E;
                ws[1 * 64 + t] = wv.y * LOG2E;
                ws[2 * 64 + t] = wv.z * LOG2E;
                ws[3 * 64 + t] = wv.w * LOG2E;
            }
            __syncthreads();
#pragma unroll
            for (int jj = 0; jj < 4; ++jj) {
                float4 xb = *(float4*)&xs[jj * 64 + tb * 4];
                float4 wb = *(float4*)&ws[jj * 64 + th * 4];
                float xa[4] = {xb.x, xb.y, xb.z, xb.w};
                float wa[4] = {wb.x, wb.y, wb.z, wb.w};
#pragma unroll
                for (int bi = 0; bi < 4; ++bi)
#pragma unroll
                    for (int hh = 0; hh < 4; ++hh)
                        acc[bi][hh] = fmaf(xa[bi], wa[hh], acc[bi][hh]);
            }
        }
        float* dst = G + (size_t)r * BH_;
#pragma unroll
        for (int bi = 0; bi < 4; ++bi) {
            float4 o = make_float4(acc[bi][0], acc[bi][1], acc[bi][2], acc[bi][3]);
            *(float4*)(dst + (size_t)(b0 + tb * 4 + bi) * H_ + h0 + th * 4) = o;
        }
    }
}

// ---------- DPP reduce: both 32-lane halves simultaneously ----------
template <int CTRL>
__device__ __forceinline__ float dpp_add(float p) {
    int s = __builtin_amdgcn_update_dpp(0, __float_as_int(p), CTRL, 0xf, 0xf, true);
    return p + __int_as_float(s);
}
__device__ __forceinline__ float reduce_halves(float p) {
    p = dpp_add<0x111>(p);
    p = dpp_add<0x112>(p);
    p = dpp_add<0x114>(p);
    p = dpp_add<0x118>(p);
    p = dpp_add<0x142>(p);   // lane31 = sum(0..31), lane63 = sum(32..63)
    return p;
}

// 8 packed bf16 (uint4) -> 8 floats
__device__ __forceinline__ void cvt8(uint4 u, float4& a, float4& b) {
    a.x = __uint_as_float(u.x << 16);
    a.y = __uint_as_float(u.x & 0xFFFF0000u);
    a.z = __uint_as_float(u.y << 16);
    a.w = __uint_as_float(u.y & 0xFFFF0000u);
    b.x = __uint_as_float(u.z << 16);
    b.y = __uint_as_float(u.z & 0xFFFF0000u);
    b.z = __uint_as_float(u.w << 16);
    b.w = __uint_as_float(u.w & 0xFFFF0000u);
}

// ---------- main scan: R7 geometry, hw exp2, bf16 VW stream ----------
__global__ __launch_bounds__(256, 6) void nade_main(
    const float* __restrict__ px,            // [B, D]
    const float* __restrict__ c,             // [H]
    const unsigned short* __restrict__ VWb,  // bf16 images
    const float* __restrict__ G,             // [5][B][H] (log2 domain)
    float* __restrict__ part)                // [4][B][D]
{
    const int lane = threadIdx.x & 63;
    const int wid  = threadIdx.x >> 6;
    const int gw   = blockIdx.x * 4 + wid;   // 0..12287
    const int s    = gw % 6;
    const int r4   = gw / 6;                 // 0..2047
    const int hb   = r4 & 3;
    const int rp   = r4 >> 2;                // 0..511
    const int half = lane >> 5;
    const int row  = rp * 2 + half;
    const int hl   = lane & 31;
    const int h0   = hb * 256 + hl * 8;

    const int i0s = seg_bound(s), i1s = seg_bound(s + 1);

    // A (log2 domain) = c*log2e + sum_{r<s} G_r
    float A[8];
    {
        float4 c0 = *(const float4*)(c + h0);
        float4 c1 = *(const float4*)(c + h0 + 4);
        A[0] = c0.x * LOG2E; A[1] = c0.y * LOG2E; A[2] = c0.z * LOG2E; A[3] = c0.w * LOG2E;
        A[4] = c1.x * LOG2E; A[5] = c1.y * LOG2E; A[6] = c1.z * LOG2E; A[7] = c1.w * LOG2E;
        for (int r = 0; r < s; ++r) {
            const float* gp = G + (size_t)r * BH_ + (size_t)row * H_ + h0;
            float4 g0 = *(const float4*)(gp);
            float4 g1 = *(const float4*)(gp + 4);
            A[0] += g0.x; A[1] += g0.y; A[2] += g0.z; A[3] += g0.w;
            A[4] += g1.x; A[5] += g1.y; A[6] += g1.z; A[7] += g1.w;
        }
    }

    const float* xp = px + (size_t)row * D_;
    float*       pp = part + ((size_t)hb * B_ + row) * D_;
    // uint4-granular pointer: image = 64 uint4; lane V chunk at +hl, W chunk at +32+hl
    const uint4* vw = (const uint4*)VWb + ((size_t)i0s * 4 + hb) * 64 + hl;

    // one step (8 h): hw exp2, grouped rcp over 8 q's; clamp exp arg to 15
    auto step8 = [&A](const float4& v0, const float4& v1,
                      const float4& w0, const float4& w1, float xi) -> float {
        float va[8] = {v0.x, v0.y, v0.z, v0.w, v1.x, v1.y, v1.z, v1.w};
        float wa[8] = {w0.x, w0.y, w0.z, w0.w, w1.x, w1.y, w1.z, w1.w};
        float q[8];
#pragma unroll
        for (int k = 0; k < 8; ++k) {
            float e = __builtin_amdgcn_exp2f(fminf(15.f, -A[k]));
            q[k] = 1.f + e;
            A[k] = fmaf(wa[k], xi, A[k]);
        }
        float a01 = fmaf(va[0], q[1], va[1] * q[0]);
        float a23 = fmaf(va[2], q[3], va[3] * q[2]);
        float a45 = fmaf(va[4], q[5], va[5] * q[4]);
        float a67 = fmaf(va[6], q[7], va[7] * q[6]);
        float q01 = q[0] * q[1], q23 = q[2] * q[3];
        float q45 = q[4] * q[5], q67 = q[6] * q[7];
        float n0123 = fmaf(a01, q23, a23 * q01);
        float n4567 = fmaf(a45, q67, a67 * q45);
        float q0123 = q01 * q23, q4567 = q45 * q67;
        float r = __builtin_amdgcn_rcpf(q0123 * q4567);
        float n = fmaf(n0123, q4567, n4567 * q0123);
        return n * r;
    };

    // preload current raw quads + first x group
    uint4 uv = vw[0], uw = vw[32];
    vw += 256;
    float4 xq = *(const float4*)(xp + i0s);

    for (int ib = i0s; ib < i1s; ib += 4) {     // all segment lengths %4 == 0
        int xb = (ib + 4 < i1s) ? (ib + 4) : i0s;
        float4 xq_n = *(const float4*)(xp + xb);
        float xa[4] = {xq.x, xq.y, xq.z, xq.w};
        float pr[4];
#pragma unroll
        for (int j = 0; j < 4; ++j) {
            uint4 uvn = vw[0], uwn = vw[32];    // prefetch next step (image 784..787 padded)
            vw += 256;
            float4 v0, v1, w0, w1;
            cvt8(uv, v0, v1);
            cvt8(uw, w0, w1);
            float p = step8(v0, v1, w0, w1, xa[j]);
            pr[j] = reduce_halves(p);
            uv = uvn; uw = uwn;
        }
        if (hl == 31) *(float4*)(pp + ib) = make_float4(pr[0], pr[1], pr[2], pr[3]);
        xq = xq_n;
    }
}

// ---------- epilogue: out[row][i] = bias[i] + sum_hb part[hb][row][i] ----------
__global__ __launch_bounds__(256) void reduce_out(const float* __restrict__ part,
                                                  const float* __restrict__ bias,
                                                  float* __restrict__ out) {
    int t = blockIdx.x * 256 + threadIdx.x;
    if (t >= B_ * (D_ / 4)) return;
    int row = t / (D_ / 4);
    int ic  = (t - row * (D_ / 4)) * 4;
    float4 acc = *(const float4*)(bias + ic);
    const float* p = part + (size_t)row * D_ + ic;
#pragma unroll
    for (int hb = 0; hb < 4; ++hb) {
        float4 v = *(const float4*)(p + (size_t)hb * B_ * D_);
        acc.x += v.x; acc.y += v.y; acc.z += v.z; acc.w += v.w;
    }
    *(float4*)(out + (size_t)row * D_ + ic) = acc;
}

extern "C" void kernel_launch(void* const* d_in, const int* in_sizes, int n_in,
                              void* d_out, int out_size, void* d_ws, size_t ws_size,
                              hipStream_t stream) {
    const float* px   = (const float*)d_in[0];  // [B, D]
    const float* W    = (const float*)d_in[1];  // [H, D]
    const float* c    = (const float*)d_in[2];  // [H]
    const float* V    = (const float*)d_in[3];  // [D, H]
    const float* bias = (const float*)d_in[4];  // [D]
    float* out = (float*)d_out;                 // [B, D]

    unsigned short* VWb = (unsigned short*)d_ws;              // 788*4*512 ushorts = 3.23 MB
    float* G    = (float*)((char*)d_ws + (size_t)788 * 4096); // [5][B][H]
    float* part = G + (size_t)5 * BH_;                        // [4][B][D]

    prep<<<dim3(2080), 256, 0, stream>>>(V, W, px, VWb, G);

    // 3072 blocks x 4 waves = 12288 waves = 2 residency rounds at 6 waves/SIMD
    nade_main<<<dim3(3072), 256, 0, stream>>>(px, c, VWb, G, part);

    reduce_out<<<dim3((B_ * (D_ / 4) + 255) / 256), 256, 0, stream>>>(part, bias, out);
}

// Round 12
// 304.184 us; speedup vs baseline: 1.4529x; 1.0190x over previous
//
#include <hip/hip_runtime.h>
#include <stdint.h>

#define B_ 1024
#define D_ 784
#define H_ 1024
#define BH_ (B_ * H_)
#define LOG2E 1.4426950408889634f

// Segments: {0,132,264,396,528,656,784}; G ranges: first 5 spans.
// VWb: per (step i, hb) a 1KB image of 512 ushorts: [0,256) = V bf16, [256,512) = W*log2e bf16.
// ws: VWb [788][4][512] ushort 3.23 MB | G [5][B][H] fp32 21 MB | part [4][B][D] 12.8 MB

__device__ __forceinline__ unsigned short bf16_rne(float x) {
    unsigned b = __float_as_uint(x);
    return (unsigned short)((b + 0x7FFFu + ((b >> 16) & 1u)) >> 16);
}

__device__ __forceinline__ int seg_bound(int s) {
    const int b[7] = {0, 132, 264, 396, 528, 656, 784};
    return b[s];
}

// ---------- fat prep ----------
__global__ __launch_bounds__(256) void prep(const float* __restrict__ V,
                                            const float* __restrict__ W,
                                            const float* __restrict__ px,
                                            unsigned short* __restrict__ VWb,
                                            float* __restrict__ G) {
    __shared__ float smem[32 * 33];
    const int t = threadIdx.x;

    if (blockIdx.x < 800) {
        int i0 = (blockIdx.x % 25) * 32;
        int h0 = (blockIdx.x / 25) * 32;
        int tx = t & 31, ty = t >> 5;   // 32 x 8
        int hb = h0 >> 8, hr = h0 & 255;
#pragma unroll
        for (int j = 0; j < 4; ++j) {
            int i = i0 + ty + j * 8;
            if (i < D_)
                VWb[((size_t)i * 4 + hb) * 512 + hr + tx] = bf16_rne(V[(size_t)i * H_ + h0 + tx]);
        }
#pragma unroll
        for (int j = 0; j < 4; ++j) {
            int h = h0 + ty + j * 8;
            int i = i0 + tx;
            float v = 0.f;
            if (i < D_) v = W[(size_t)h * D_ + i] * LOG2E;
            smem[(ty + j * 8) * 33 + tx] = v;
        }
        __syncthreads();
#pragma unroll
        for (int j = 0; j < 4; ++j) {
            int i = i0 + ty + j * 8;
            if (i < D_)
                VWb[((size_t)i * 4 + hb) * 512 + 256 + hr + tx] = bf16_rne(smem[tx * 33 + ty + j * 8]);
        }
    } else {
        float* xs = smem;          // [4][64]
        float* ws = smem + 256;    // [4][64]
        int idx = blockIdx.x - 800;
        int r   = idx >> 8;                       // 0..4
        int b0  = (idx & 15) * 64;
        int h0  = ((idx >> 4) & 15) * 64;
        int j0s = seg_bound(r), j1s = seg_bound(r + 1);

        const int tb = t >> 4, th = t & 15;       // 16x16, each 4b x 4h
        float acc[4][4];
#pragma unroll
        for (int bi = 0; bi < 4; ++bi)
#pragma unroll
            for (int hh = 0; hh < 4; ++hh) acc[bi][hh] = 0.f;

        for (int j0 = j0s; j0 < j1s; j0 += 4) {
            float xv = px[(size_t)(b0 + (t >> 2)) * D_ + j0 + (t & 3)];
            float4 wv = make_float4(0, 0, 0, 0);
            if (t < 64) wv = *(const float4*)(W + (size_t)(h0 + t) * D_ + j0);
            __syncthreads();
            xs[(t & 3) * 64 + (t >> 2)] = xv;
            if (t < 64) {
                ws[0 * 64 + t] = wv.x * LOG2E;
                ws[1 * 64 + t] = wv.y * LOG2E;
                ws[2 * 64 + t] = wv.z * LOG2E;
                ws[3 * 64 + t] = wv.w * LOG2E;
            }
            __syncthreads();
#pragma unroll
            for (int jj = 0; jj < 4; ++jj) {
                float4 xb = *(float4*)&xs[jj * 64 + tb * 4];
                float4 wb = *(float4*)&ws[jj * 64 + th * 4];
                float xa[4] = {xb.x, xb.y, xb.z, xb.w};
                float wa[4] = {wb.x, wb.y, wb.z, wb.w};
#pragma unroll
                for (int bi = 0; bi < 4; ++bi)
#pragma unroll
                    for (int hh = 0; hh < 4; ++hh)
                        acc[bi][hh] = fmaf(xa[bi], wa[hh], acc[bi][hh]);
            }
        }
        float* dst = G + (size_t)r * BH_;
#pragma unroll
        for (int bi = 0; bi < 4; ++bi) {
            float4 o = make_float4(acc[bi][0], acc[bi][1], acc[bi][2], acc[bi][3]);
            *(float4*)(dst + (size_t)(b0 + tb * 4 + bi) * H_ + h0 + th * 4) = o;
        }
    }
}

// ---------- DPP reduce: both 32-lane halves simultaneously ----------
template <int CTRL>
__device__ __forceinline__ float dpp_add(float p) {
    int s = __builtin_amdgcn_update_dpp(0, __float_as_int(p), CTRL, 0xf, 0xf, true);
    return p + __int_as_float(s);
}
__device__ __forceinline__ float reduce_halves(float p) {
    p = dpp_add<0x111>(p);
    p = dpp_add<0x112>(p);
    p = dpp_add<0x114>(p);
    p = dpp_add<0x118>(p);
    p = dpp_add<0x142>(p);   // lane31 = sum(0..31), lane63 = sum(32..63)
    return p;
}

// 8 packed bf16 (uint4) -> 8 floats; high elements keep junk low-mantissa bits
// (<= 2^-7 relative, ~2 bf16 ulp — accepted; saves 8 AND ops per cvt8 pair)
__device__ __forceinline__ void cvt8(uint4 u, float4& a, float4& b) {
    a.x = __uint_as_float(u.x << 16);
    a.y = __uint_as_float(u.x);
    a.z = __uint_as_float(u.y << 16);
    a.w = __uint_as_float(u.y);
    b.x = __uint_as_float(u.z << 16);
    b.y = __uint_as_float(u.z);
    b.z = __uint_as_float(u.w << 16);
    b.w = __uint_as_float(u.w);
}

// ---------- main scan: R11 + slim cvt8 + 8 waves/SIMD ----------
__global__ __launch_bounds__(256, 8) void nade_main(
    const float* __restrict__ px,            // [B, D]
    const float* __restrict__ c,             // [H]
    const unsigned short* __restrict__ VWb,  // bf16 images
    const float* __restrict__ G,             // [5][B][H] (log2 domain)
    float* __restrict__ part)                // [4][B][D]
{
    const int lane = threadIdx.x & 63;
    const int wid  = threadIdx.x >> 6;
    const int gw   = blockIdx.x * 4 + wid;   // 0..12287
    const int s    = gw % 6;
    const int r4   = gw / 6;                 // 0..2047
    const int hb   = r4 & 3;
    const int rp   = r4 >> 2;                // 0..511
    const int half = lane >> 5;
    const int row  = rp * 2 + half;
    const int hl   = lane & 31;
    const int h0   = hb * 256 + hl * 8;

    const int i0s = seg_bound(s), i1s = seg_bound(s + 1);

    // A (log2 domain) = c*log2e + sum_{r<s} G_r
    float A[8];
    {
        float4 c0 = *(const float4*)(c + h0);
        float4 c1 = *(const float4*)(c + h0 + 4);
        A[0] = c0.x * LOG2E; A[1] = c0.y * LOG2E; A[2] = c0.z * LOG2E; A[3] = c0.w * LOG2E;
        A[4] = c1.x * LOG2E; A[5] = c1.y * LOG2E; A[6] = c1.z * LOG2E; A[7] = c1.w * LOG2E;
        for (int r = 0; r < s; ++r) {
            const float* gp = G + (size_t)r * BH_ + (size_t)row * H_ + h0;
            float4 g0 = *(const float4*)(gp);
            float4 g1 = *(const float4*)(gp + 4);
            A[0] += g0.x; A[1] += g0.y; A[2] += g0.z; A[3] += g0.w;
            A[4] += g1.x; A[5] += g1.y; A[6] += g1.z; A[7] += g1.w;
        }
    }

    const float* xp = px + (size_t)row * D_;
    float*       pp = part + ((size_t)hb * B_ + row) * D_;
    const uint4* vw = (const uint4*)VWb + ((size_t)i0s * 4 + hb) * 64 + hl;

    // one step (8 h): hw exp2, grouped rcp over 8 q's; clamp exp arg to 15
    auto step8 = [&A](const float4& v0, const float4& v1,
                      const float4& w0, const float4& w1, float xi) -> float {
        float va[8] = {v0.x, v0.y, v0.z, v0.w, v1.x, v1.y, v1.z, v1.w};
        float wa[8] = {w0.x, w0.y, w0.z, w0.w, w1.x, w1.y, w1.z, w1.w};
        float q[8];
#pragma unroll
        for (int k = 0; k < 8; ++k) {
            float e = __builtin_amdgcn_exp2f(fminf(15.f, -A[k]));
            q[k] = 1.f + e;
            A[k] = fmaf(wa[k], xi, A[k]);
        }
        float a01 = fmaf(va[0], q[1], va[1] * q[0]);
        float a23 = fmaf(va[2], q[3], va[3] * q[2]);
        float a45 = fmaf(va[4], q[5], va[5] * q[4]);
        float a67 = fmaf(va[6], q[7], va[7] * q[6]);
        float q01 = q[0] * q[1], q23 = q[2] * q[3];
        float q45 = q[4] * q[5], q67 = q[6] * q[7];
        float n0123 = fmaf(a01, q23, a23 * q01);
        float n4567 = fmaf(a45, q67, a67 * q45);
        float q0123 = q01 * q23, q4567 = q45 * q67;
        float r = __builtin_amdgcn_rcpf(q0123 * q4567);
        float n = fmaf(n0123, q4567, n4567 * q0123);
        return n * r;
    };

    // preload current raw quads + first x group
    uint4 uv = vw[0], uw = vw[32];
    vw += 256;
    float4 xq = *(const float4*)(xp + i0s);

    for (int ib = i0s; ib < i1s; ib += 4) {     // all segment lengths %4 == 0
        int xb = (ib + 4 < i1s) ? (ib + 4) : i0s;
        float4 xq_n = *(const float4*)(xp + xb);
        float xa[4] = {xq.x, xq.y, xq.z, xq.w};
        float pr[4];
#pragma unroll
        for (int j = 0; j < 4; ++j) {
            uint4 uvn = vw[0], uwn = vw[32];    // prefetch next step (images padded past 784)
            vw += 256;
            float4 v0, v1, w0, w1;
            cvt8(uv, v0, v1);
            cvt8(uw, w0, w1);
            float p = step8(v0, v1, w0, w1, xa[j]);
            pr[j] = reduce_halves(p);
            uv = uvn; uw = uwn;
        }
        if (hl == 31) *(float4*)(pp + ib) = make_float4(pr[0], pr[1], pr[2], pr[3]);
        xq = xq_n;
    }
}

// ---------- epilogue: out[row][i] = bias[i] + sum_hb part[hb][row][i] ----------
__global__ __launch_bounds__(256) void reduce_out(const float* __restrict__ part,
                                                  const float* __restrict__ bias,
                                                  float* __restrict__ out) {
    int t = blockIdx.x * 256 + threadIdx.x;
    if (t >= B_ * (D_ / 4)) return;
    int row = t / (D_ / 4);
    int ic  = (t - row * (D_ / 4)) * 4;
    float4 acc = *(const float4*)(bias + ic);
    const float* p = part + (size_t)row * D_ + ic;
#pragma unroll
    for (int hb = 0; hb < 4; ++hb) {
        float4 v = *(const float4*)(p + (size_t)hb * B_ * D_);
        acc.x += v.x; acc.y += v.y; acc.z += v.z; acc.w += v.w;
    }
    *(float4*)(out + (size_t)row * D_ + ic) = acc;
}

extern "C" void kernel_launch(void* const* d_in, const int* in_sizes, int n_in,
                              void* d_out, int out_size, void* d_ws, size_t ws_size,
                              hipStream_t stream) {
    const float* px   = (const float*)d_in[0];  // [B, D]
    const float* W    = (const float*)d_in[1];  // [H, D]
    const float* c    = (const float*)d_in[2];  // [H]
    const float* V    = (const float*)d_in[3];  // [D, H]
    const float* bias = (const float*)d_in[4];  // [D]
    float* out = (float*)d_out;                 // [B, D]

    unsigned short* VWb = (unsigned short*)d_ws;              // 788*4*512 ushorts = 3.23 MB
    float* G    = (float*)((char*)d_ws + (size_t)788 * 4096); // [5][B][H]
    float* part = G + (size_t)5 * BH_;                        // [4][B][D]

    prep<<<dim3(2080), 256, 0, stream>>>(V, W, px, VWb, G);

    // 3072 blocks x 4 waves = 12288 waves, up to 8 waves/SIMD resident
    nade_main<<<dim3(3072), 256, 0, stream>>>(px, c, VWb, G, part);

    reduce_out<<<dim3((B_ * (D_ / 4) + 255) / 256), 256, 0, stream>>>(part, bias, out);
}

// Round 13
// 301.310 us; speedup vs baseline: 1.4667x; 1.0095x over previous
//
#include <hip/hip_runtime.h>
#include <stdint.h>

#define B_ 1024
#define D_ 784
#define H_ 1024
#define BH_ (B_ * H_)
#define LOG2E 1.4426950408889634f

// Segments: {0,136,272,400,528,656,784} (all %8); G ranges: first 5 spans.
// VWb: per (step i, hb) a 1KB image of 512 ushorts: [0,256) = V bf16, [256,512) = W*log2e bf16.
// ws: VWb [788][4][512] ushort 3.23 MB | G [5][B][H] fp32 21 MB | part [4][B][D] 12.8 MB

__device__ __forceinline__ unsigned short bf16_rne(float x) {
    unsigned b = __float_as_uint(x);
    return (unsigned short)((b + 0x7FFFu + ((b >> 16) & 1u)) >> 16);
}

__device__ __forceinline__ int seg_bound(int s) {
    const int b[7] = {0, 136, 272, 400, 528, 656, 784};
    return b[s];
}

// ---------- fat prep ----------
// blocks [0,800): build VWb (V + W^T*log2e, both bf16-RNE); blocks [800,2080): G partial GEMMs (K=8)
__global__ __launch_bounds__(256) void prep(const float* __restrict__ V,
                                            const float* __restrict__ W,
                                            const float* __restrict__ px,
                                            unsigned short* __restrict__ VWb,
                                            float* __restrict__ G) {
    __shared__ float smem[32 * 33];
    const int t = threadIdx.x;

    if (blockIdx.x < 800) {
        int i0 = (blockIdx.x % 25) * 32;
        int h0 = (blockIdx.x / 25) * 32;
        int tx = t & 31, ty = t >> 5;   // 32 x 8
        int hb = h0 >> 8, hr = h0 & 255;
#pragma unroll
        for (int j = 0; j < 4; ++j) {
            int i = i0 + ty + j * 8;
            if (i < D_)
                VWb[((size_t)i * 4 + hb) * 512 + hr + tx] = bf16_rne(V[(size_t)i * H_ + h0 + tx]);
        }
#pragma unroll
        for (int j = 0; j < 4; ++j) {
            int h = h0 + ty + j * 8;
            int i = i0 + tx;
            float v = 0.f;
            if (i < D_) v = W[(size_t)h * D_ + i] * LOG2E;
            smem[(ty + j * 8) * 33 + tx] = v;
        }
        __syncthreads();
#pragma unroll
        for (int j = 0; j < 4; ++j) {
            int i = i0 + ty + j * 8;
            if (i < D_)
                VWb[((size_t)i * 4 + hb) * 512 + 256 + hr + tx] = bf16_rne(smem[tx * 33 + ty + j * 8]);
        }
    } else {
        float* xs = smem;          // [8][64] = 512
        float* ws = smem + 512;    // [8][64] = 512 (smem has 1056 floats)
        int idx = blockIdx.x - 800;
        int r   = idx >> 8;                       // 0..4
        int b0  = (idx & 15) * 64;
        int h0  = ((idx >> 4) & 15) * 64;
        int j0s = seg_bound(r), j1s = seg_bound(r + 1);

        const int tb = t >> 4, th = t & 15;       // 16x16, each 4b x 4h
        float acc[4][4];
#pragma unroll
        for (int bi = 0; bi < 4; ++bi)
#pragma unroll
            for (int hh = 0; hh < 4; ++hh) acc[bi][hh] = 0.f;

        const int xb = t >> 3;                    // 0..31
        const int xj = t & 7;                     // 0..7
        const int wh = t >> 1, wj = (t & 1) * 4;  // for t < 128

        for (int j0 = j0s; j0 < j1s; j0 += 8) {   // range lengths all %8 == 0
            float xv0 = px[(size_t)(b0 + xb) * D_ + j0 + xj];
            float xv1 = px[(size_t)(b0 + 32 + xb) * D_ + j0 + xj];
            float4 wv = make_float4(0, 0, 0, 0);
            if (t < 128) wv = *(const float4*)(W + (size_t)(h0 + wh) * D_ + j0 + wj);
            __syncthreads();
            xs[xj * 64 + xb]      = xv0;
            xs[xj * 64 + 32 + xb] = xv1;
            if (t < 128) {
                ws[(wj + 0) * 64 + wh] = wv.x * LOG2E;
                ws[(wj + 1) * 64 + wh] = wv.y * LOG2E;
                ws[(wj + 2) * 64 + wh] = wv.z * LOG2E;
                ws[(wj + 3) * 64 + wh] = wv.w * LOG2E;
            }
            __syncthreads();
#pragma unroll
            for (int jj = 0; jj < 8; ++jj) {
                float4 xq = *(float4*)&xs[jj * 64 + tb * 4];
                float4 wq = *(float4*)&ws[jj * 64 + th * 4];
                float xa[4] = {xq.x, xq.y, xq.z, xq.w};
                float wa[4] = {wq.x, wq.y, wq.z, wq.w};
#pragma unroll
                for (int bi = 0; bi < 4; ++bi)
#pragma unroll
                    for (int hh = 0; hh < 4; ++hh)
                        acc[bi][hh] = fmaf(xa[bi], wa[hh], acc[bi][hh]);
            }
        }
        float* dst = G + (size_t)r * BH_;
#pragma unroll
        for (int bi = 0; bi < 4; ++bi) {
            float4 o = make_float4(acc[bi][0], acc[bi][1], acc[bi][2], acc[bi][3]);
            *(float4*)(dst + (size_t)(b0 + tb * 4 + bi) * H_ + h0 + th * 4) = o;
        }
    }
}

// ---------- DPP reduce: both 32-lane halves simultaneously ----------
template <int CTRL>
__device__ __forceinline__ float dpp_add(float p) {
    int s = __builtin_amdgcn_update_dpp(0, __float_as_int(p), CTRL, 0xf, 0xf, true);
    return p + __int_as_float(s);
}
__device__ __forceinline__ float reduce_halves(float p) {
    p = dpp_add<0x111>(p);
    p = dpp_add<0x112>(p);
    p = dpp_add<0x114>(p);
    p = dpp_add<0x118>(p);
    p = dpp_add<0x142>(p);   // lane31 = sum(0..31), lane63 = sum(32..63)
    return p;
}

// 8 packed bf16 (uint4) -> 8 floats; high elements keep junk low-mantissa bits
__device__ __forceinline__ void cvt8(uint4 u, float4& a, float4& b) {
    a.x = __uint_as_float(u.x << 16);
    a.y = __uint_as_float(u.x);
    a.z = __uint_as_float(u.y << 16);
    a.w = __uint_as_float(u.y);
    b.x = __uint_as_float(u.z << 16);
    b.y = __uint_as_float(u.z);
    b.z = __uint_as_float(u.w << 16);
    b.w = __uint_as_float(u.w);
}

// ---------- main scan (unchanged from R12 except seg_bound table) ----------
__global__ __launch_bounds__(256, 8) void nade_main(
    const float* __restrict__ px,            // [B, D]
    const float* __restrict__ c,             // [H]
    const unsigned short* __restrict__ VWb,  // bf16 images
    const float* __restrict__ G,             // [5][B][H] (log2 domain)
    float* __restrict__ part)                // [4][B][D]
{
    const int lane = threadIdx.x & 63;
    const int wid  = threadIdx.x >> 6;
    const int gw   = blockIdx.x * 4 + wid;   // 0..12287
    const int s    = gw % 6;
    const int r4   = gw / 6;                 // 0..2047
    const int hb   = r4 & 3;
    const int rp   = r4 >> 2;                // 0..511
    const int half = lane >> 5;
    const int row  = rp * 2 + half;
    const int hl   = lane & 31;
    const int h0   = hb * 256 + hl * 8;

    const int i0s = seg_bound(s), i1s = seg_bound(s + 1);

    // A (log2 domain) = c*log2e + sum_{r<s} G_r
    float A[8];
    {
        float4 c0 = *(const float4*)(c + h0);
        float4 c1 = *(const float4*)(c + h0 + 4);
        A[0] = c0.x * LOG2E; A[1] = c0.y * LOG2E; A[2] = c0.z * LOG2E; A[3] = c0.w * LOG2E;
        A[4] = c1.x * LOG2E; A[5] = c1.y * LOG2E; A[6] = c1.z * LOG2E; A[7] = c1.w * LOG2E;
        for (int r = 0; r < s; ++r) {
            const float* gp = G + (size_t)r * BH_ + (size_t)row * H_ + h0;
            float4 g0 = *(const float4*)(gp);
            float4 g1 = *(const float4*)(gp + 4);
            A[0] += g0.x; A[1] += g0.y; A[2] += g0.z; A[3] += g0.w;
            A[4] += g1.x; A[5] += g1.y; A[6] += g1.z; A[7] += g1.w;
        }
    }

    const float* xp = px + (size_t)row * D_;
    float*       pp = part + ((size_t)hb * B_ + row) * D_;
    const uint4* vw = (const uint4*)VWb + ((size_t)i0s * 4 + hb) * 64 + hl;

    // one step (8 h): hw exp2, grouped rcp over 8 q's; clamp exp arg to 15
    auto step8 = [&A](const float4& v0, const float4& v1,
                      const float4& w0, const float4& w1, float xi) -> float {
        float va[8] = {v0.x, v0.y, v0.z, v0.w, v1.x, v1.y, v1.z, v1.w};
        float wa[8] = {w0.x, w0.y, w0.z, w0.w, w1.x, w1.y, w1.z, w1.w};
        float q[8];
#pragma unroll
        for (int k = 0; k < 8; ++k) {
            float e = __builtin_amdgcn_exp2f(fminf(15.f, -A[k]));
            q[k] = 1.f + e;
            A[k] = fmaf(wa[k], xi, A[k]);
        }
        float a01 = fmaf(va[0], q[1], va[1] * q[0]);
        float a23 = fmaf(va[2], q[3], va[3] * q[2]);
        float a45 = fmaf(va[4], q[5], va[5] * q[4]);
        float a67 = fmaf(va[6], q[7], va[7] * q[6]);
        float q01 = q[0] * q[1], q23 = q[2] * q[3];
        float q45 = q[4] * q[5], q67 = q[6] * q[7];
        float n0123 = fmaf(a01, q23, a23 * q01);
        float n4567 = fmaf(a45, q67, a67 * q45);
        float q0123 = q01 * q23, q4567 = q45 * q67;
        float r = __builtin_amdgcn_rcpf(q0123 * q4567);
        float n = fmaf(n0123, q4567, n4567 * q0123);
        return n * r;
    };

    // preload current raw quads + first x group
    uint4 uv = vw[0], uw = vw[32];
    vw += 256;
    float4 xq = *(const float4*)(xp + i0s);

    for (int ib = i0s; ib < i1s; ib += 4) {     // all segment lengths %4 == 0
        int xb = (ib + 4 < i1s) ? (ib + 4) : i0s;
        float4 xq_n = *(const float4*)(xp + xb);
        float xa[4] = {xq.x, xq.y, xq.z, xq.w};
        float pr[4];
#pragma unroll
        for (int j = 0; j < 4; ++j) {
            uint4 uvn = vw[0], uwn = vw[32];    // prefetch next step (images padded past 784)
            vw += 256;
            float4 v0, v1, w0, w1;
            cvt8(uv, v0, v1);
            cvt8(uw, w0, w1);
            float p = step8(v0, v1, w0, w1, xa[j]);
            pr[j] = reduce_halves(p);
            uv = uvn; uw = uwn;
        }
        if (hl == 31) *(float4*)(pp + ib) = make_float4(pr[0], pr[1], pr[2], pr[3]);
        xq = xq_n;
    }
}

// ---------- epilogue: out[row][i] = bias[i] + sum_hb part[hb][row][i] ----------
__global__ __launch_bounds__(256) void reduce_out(const float* __restrict__ part,
                                                  const float* __restrict__ bias,
                                                  float* __restrict__ out) {
    int t = blockIdx.x * 256 + threadIdx.x;
    if (t >= B_ * (D_ / 4)) return;
    int row = t / (D_ / 4);
    int ic  = (t - row * (D_ / 4)) * 4;
    float4 acc = *(const float4*)(bias + ic);
    const float* p = part + (size_t)row * D_ + ic;
#pragma unroll
    for (int hb = 0; hb < 4; ++hb) {
        float4 v = *(const float4*)(p + (size_t)hb * B_ * D_);
        acc.x += v.x; acc.y += v.y; acc.z += v.z; acc.w += v.w;
    }
    *(float4*)(out + (size_t)row * D_ + ic) = acc;
}

extern "C" void kernel_launch(void* const* d_in, const int* in_sizes, int n_in,
                              void* d_out, int out_size, void* d_ws, size_t ws_size,
                              hipStream_t stream) {
    const float* px   = (const float*)d_in[0];  // [B, D]
    const float* W    = (const float*)d_in[1];  // [H, D]
    const float* c    = (const float*)d_in[2];  // [H]
    const float* V    = (const float*)d_in[3];  // [D, H]
    const float* bias = (const float*)d_in[4];  // [D]
    float* out = (float*)d_out;                 // [B, D]

    unsigned short* VWb = (unsigned short*)d_ws;              // 788*4*512 ushorts = 3.23 MB
    float* G    = (float*)((char*)d_ws + (size_t)788 * 4096); // [5][B][H]
    float* part = G + (size_t)5 * BH_;                        // [4][B][D]

    prep<<<dim3(2080), 256, 0, stream>>>(V, W, px, VWb, G);

    // 3072 blocks x 4 waves = 12288 waves
    nade_main<<<dim3(3072), 256, 0, stream>>>(px, c, VWb, G, part);

    reduce_out<<<dim3((B_ * (D_ / 4) + 255) / 256), 256, 0, stream>>>(part, bias, out);
}

// Round 14
// 300.640 us; speedup vs baseline: 1.4700x; 1.0022x over previous
//
#include <hip/hip_runtime.h>
#include <stdint.h>

#define B_ 1024
#define D_ 784
#define H_ 1024
#define BH_ (B_ * H_)
#define LOG2E 1.4426950408889634f

// Segments: {0,136,272,400,528,656,784} (all %8); G ranges: first 5 spans.
// VWb: per (step i, hb) a 1KB image of 512 ushorts: [0,256) = V bf16, [256,512) = W*log2e bf16.
// ws: VWb [788][4][512] ushort 3.23 MB | G [5][B][H] fp32 21 MB   (part buffer eliminated)

__device__ __forceinline__ unsigned short bf16_rne(float x) {
    unsigned b = __float_as_uint(x);
    return (unsigned short)((b + 0x7FFFu + ((b >> 16) & 1u)) >> 16);
}

__device__ __forceinline__ int seg_bound(int s) {
    const int b[7] = {0, 136, 272, 400, 528, 656, 784};
    return b[s];
}

// ---------- fat prep (identical to R13) ----------
__global__ __launch_bounds__(256) void prep(const float* __restrict__ V,
                                            const float* __restrict__ W,
                                            const float* __restrict__ px,
                                            unsigned short* __restrict__ VWb,
                                            float* __restrict__ G) {
    __shared__ float smem[1056];
    const int t = threadIdx.x;

    if (blockIdx.x < 800) {
        int i0 = (blockIdx.x % 25) * 32;
        int h0 = (blockIdx.x / 25) * 32;
        int tx = t & 31, ty = t >> 5;   // 32 x 8
        int hb = h0 >> 8, hr = h0 & 255;
#pragma unroll
        for (int j = 0; j < 4; ++j) {
            int i = i0 + ty + j * 8;
            if (i < D_)
                VWb[((size_t)i * 4 + hb) * 512 + hr + tx] = bf16_rne(V[(size_t)i * H_ + h0 + tx]);
        }
#pragma unroll
        for (int j = 0; j < 4; ++j) {
            int h = h0 + ty + j * 8;
            int i = i0 + tx;
            float v = 0.f;
            if (i < D_) v = W[(size_t)h * D_ + i] * LOG2E;
            smem[(ty + j * 8) * 33 + tx] = v;
        }
        __syncthreads();
#pragma unroll
        for (int j = 0; j < 4; ++j) {
            int i = i0 + ty + j * 8;
            if (i < D_)
                VWb[((size_t)i * 4 + hb) * 512 + 256 + hr + tx] = bf16_rne(smem[tx * 33 + ty + j * 8]);
        }
    } else {
        float* xs = smem;          // [8][64]
        float* ws = smem + 512;    // [8][64]
        int idx = blockIdx.x - 800;
        int r   = idx >> 8;                       // 0..4
        int b0  = (idx & 15) * 64;
        int h0  = ((idx >> 4) & 15) * 64;
        int j0s = seg_bound(r), j1s = seg_bound(r + 1);

        const int tb = t >> 4, th = t & 15;       // 16x16, each 4b x 4h
        float acc[4][4];
#pragma unroll
        for (int bi = 0; bi < 4; ++bi)
#pragma unroll
            for (int hh = 0; hh < 4; ++hh) acc[bi][hh] = 0.f;

        const int xb = t >> 3;                    // 0..31
        const int xj = t & 7;                     // 0..7
        const int wh = t >> 1, wj = (t & 1) * 4;  // for t < 128

        for (int j0 = j0s; j0 < j1s; j0 += 8) {   // range lengths all %8 == 0
            float xv0 = px[(size_t)(b0 + xb) * D_ + j0 + xj];
            float xv1 = px[(size_t)(b0 + 32 + xb) * D_ + j0 + xj];
            float4 wv = make_float4(0, 0, 0, 0);
            if (t < 128) wv = *(const float4*)(W + (size_t)(h0 + wh) * D_ + j0 + wj);
            __syncthreads();
            xs[xj * 64 + xb]      = xv0;
            xs[xj * 64 + 32 + xb] = xv1;
            if (t < 128) {
                ws[(wj + 0) * 64 + wh] = wv.x * LOG2E;
                ws[(wj + 1) * 64 + wh] = wv.y * LOG2E;
                ws[(wj + 2) * 64 + wh] = wv.z * LOG2E;
                ws[(wj + 3) * 64 + wh] = wv.w * LOG2E;
            }
            __syncthreads();
#pragma unroll
            for (int jj = 0; jj < 8; ++jj) {
                float4 xq = *(float4*)&xs[jj * 64 + tb * 4];
                float4 wq = *(float4*)&ws[jj * 64 + th * 4];
                float xa[4] = {xq.x, xq.y, xq.z, xq.w};
                float wa[4] = {wq.x, wq.y, wq.z, wq.w};
#pragma unroll
                for (int bi = 0; bi < 4; ++bi)
#pragma unroll
                    for (int hh = 0; hh < 4; ++hh)
                        acc[bi][hh] = fmaf(xa[bi], wa[hh], acc[bi][hh]);
            }
        }
        float* dst = G + (size_t)r * BH_;
#pragma unroll
        for (int bi = 0; bi < 4; ++bi) {
            float4 o = make_float4(acc[bi][0], acc[bi][1], acc[bi][2], acc[bi][3]);
            *(float4*)(dst + (size_t)(b0 + tb * 4 + bi) * H_ + h0 + th * 4) = o;
        }
    }
}

// ---------- DPP reduce: both 32-lane halves simultaneously ----------
template <int CTRL>
__device__ __forceinline__ float dpp_add(float p) {
    int s = __builtin_amdgcn_update_dpp(0, __float_as_int(p), CTRL, 0xf, 0xf, true);
    return p + __int_as_float(s);
}
__device__ __forceinline__ float reduce_halves(float p) {
    p = dpp_add<0x111>(p);
    p = dpp_add<0x112>(p);
    p = dpp_add<0x114>(p);
    p = dpp_add<0x118>(p);
    p = dpp_add<0x142>(p);   // lane31 = sum(0..31), lane63 = sum(32..63)
    return p;
}

// 8 packed bf16 (uint4) -> 8 floats; high elements keep junk low-mantissa bits
__device__ __forceinline__ void cvt8(uint4 u, float4& a, float4& b) {
    a.x = __uint_as_float(u.x << 16);
    a.y = __uint_as_float(u.x);
    a.z = __uint_as_float(u.y << 16);
    a.w = __uint_as_float(u.y);
    b.x = __uint_as_float(u.z << 16);
    b.y = __uint_as_float(u.z);
    b.z = __uint_as_float(u.w << 16);
    b.w = __uint_as_float(u.w);
}

// ---------- main scan: block = (s, row-pair), 4 waves = 4 hb; in-block hb reduce ----------
__global__ __launch_bounds__(256, 8) void nade_main(
    const float* __restrict__ px,            // [B, D]
    const float* __restrict__ c,             // [H]
    const unsigned short* __restrict__ VWb,  // bf16 images
    const float* __restrict__ G,             // [5][B][H] (log2 domain)
    const float* __restrict__ bias,          // [D]
    float* __restrict__ out)                 // [B, D] — written directly
{
    __shared__ float4 red[2][4][2];          // [parity][wid][half] — 256 B

    const int lane = threadIdx.x & 63;
    const int wid  = threadIdx.x >> 6;       // = hb
    const int bid  = blockIdx.x;             // 0..3071
    const int s    = bid % 6;
    const int rp   = bid / 6;                // 0..511
    const int half = lane >> 5;
    const int row  = rp * 2 + half;
    const int hl   = lane & 31;
    const int h0   = wid * 256 + hl * 8;

    const int i0s = seg_bound(s), i1s = seg_bound(s + 1);

    // A (log2 domain) = c*log2e + sum_{r<s} G_r
    float A[8];
    {
        float4 c0 = *(const float4*)(c + h0);
        float4 c1 = *(const float4*)(c + h0 + 4);
        A[0] = c0.x * LOG2E; A[1] = c0.y * LOG2E; A[2] = c0.z * LOG2E; A[3] = c0.w * LOG2E;
        A[4] = c1.x * LOG2E; A[5] = c1.y * LOG2E; A[6] = c1.z * LOG2E; A[7] = c1.w * LOG2E;
        for (int r = 0; r < s; ++r) {
            const float* gp = G + (size_t)r * BH_ + (size_t)row * H_ + h0;
            float4 g0 = *(const float4*)(gp);
            float4 g1 = *(const float4*)(gp + 4);
            A[0] += g0.x; A[1] += g0.y; A[2] += g0.z; A[3] += g0.w;
            A[4] += g1.x; A[5] += g1.y; A[6] += g1.z; A[7] += g1.w;
        }
    }

    const float* xp = px + (size_t)row * D_;
    const uint4* vw = (const uint4*)VWb + ((size_t)i0s * 4 + wid) * 64 + hl;

    // one step (8 h): hw exp2, grouped rcp over 8 q's; clamp exp arg to 15
    auto step8 = [&A](const float4& v0, const float4& v1,
                      const float4& w0, const float4& w1, float xi) -> float {
        float va[8] = {v0.x, v0.y, v0.z, v0.w, v1.x, v1.y, v1.z, v1.w};
        float wa[8] = {w0.x, w0.y, w0.z, w0.w, w1.x, w1.y, w1.z, w1.w};
        float q[8];
#pragma unroll
        for (int k = 0; k < 8; ++k) {
            float e = __builtin_amdgcn_exp2f(fminf(15.f, -A[k]));
            q[k] = 1.f + e;
            A[k] = fmaf(wa[k], xi, A[k]);
        }
        float a01 = fmaf(va[0], q[1], va[1] * q[0]);
        float a23 = fmaf(va[2], q[3], va[3] * q[2]);
        float a45 = fmaf(va[4], q[5], va[5] * q[4]);
        float a67 = fmaf(va[6], q[7], va[7] * q[6]);
        float q01 = q[0] * q[1], q23 = q[2] * q[3];
        float q45 = q[4] * q[5], q67 = q[6] * q[7];
        float n0123 = fmaf(a01, q23, a23 * q01);
        float n4567 = fmaf(a45, q67, a67 * q45);
        float q0123 = q01 * q23, q4567 = q45 * q67;
        float r = __builtin_amdgcn_rcpf(q0123 * q4567);
        float n = fmaf(n0123, q4567, n4567 * q0123);
        return n * r;
    };

    // preload current raw quads + first x group
    uint4 uv = vw[0], uw = vw[32];
    vw += 256;
    float4 xq = *(const float4*)(xp + i0s);

    for (int ib = i0s; ib < i1s; ib += 4) {     // all segment lengths %4 == 0
        int xb = (ib + 4 < i1s) ? (ib + 4) : i0s;
        float4 xq_n = *(const float4*)(xp + xb);
        float xa[4] = {xq.x, xq.y, xq.z, xq.w};
        float pr[4];
#pragma unroll
        for (int j = 0; j < 4; ++j) {
            uint4 uvn = vw[0], uwn = vw[32];    // prefetch next step (images padded past 784)
            vw += 256;
            float4 v0, v1, w0, w1;
            cvt8(uv, v0, v1);
            cvt8(uw, w0, w1);
            float p = step8(v0, v1, w0, w1, xa[j]);
            pr[j] = reduce_halves(p);
            uv = uvn; uw = uwn;
        }
        const int par = (ib >> 2) & 1;
        if (hl == 31) red[par][wid][half] = make_float4(pr[0], pr[1], pr[2], pr[3]);
        __syncthreads();
        if (threadIdx.x < 2) {                  // thread t handles logical half t (row rp*2+t)
            float4 b4 = *(const float4*)(bias + ib);
            float4 p0 = red[par][0][threadIdx.x];
            float4 p1 = red[par][1][threadIdx.x];
            float4 p2 = red[par][2][threadIdx.x];
            float4 p3 = red[par][3][threadIdx.x];
            float4 o;
            o.x = b4.x + ((p0.x + p1.x) + (p2.x + p3.x));
            o.y = b4.y + ((p0.y + p1.y) + (p2.y + p3.y));
            o.z = b4.z + ((p0.z + p1.z) + (p2.z + p3.z));
            o.w = b4.w + ((p0.w + p1.w) + (p2.w + p3.w));
            *(float4*)(out + (size_t)(rp * 2 + threadIdx.x) * D_ + ib) = o;
        }
        xq = xq_n;
    }
}

extern "C" void kernel_launch(void* const* d_in, const int* in_sizes, int n_in,
                              void* d_out, int out_size, void* d_ws, size_t ws_size,
                              hipStream_t stream) {
    const float* px   = (const float*)d_in[0];  // [B, D]
    const float* W    = (const float*)d_in[1];  // [H, D]
    const float* c    = (const float*)d_in[2];  // [H]
    const float* V    = (const float*)d_in[3];  // [D, H]
    const float* bias = (const float*)d_in[4];  // [D]
    float* out = (float*)d_out;                 // [B, D]

    unsigned short* VWb = (unsigned short*)d_ws;              // 788*4*512 ushorts = 3.23 MB
    float* G    = (float*)((char*)d_ws + (size_t)788 * 4096); // [5][B][H]

    prep<<<dim3(2080), 256, 0, stream>>>(V, W, px, VWb, G);

    // 3072 blocks x 4 waves; block = (segment, row-pair), waves = 4 hb quarters
    nade_main<<<dim3(3072), 256, 0, stream>>>(px, c, VWb, G, bias, out);
}